// Round 15
// baseline (895.783 us; speedup 1.0000x reference)
//
#include <hip/hip_runtime.h>
#include <hip/hip_bf16.h>

#define N_NODES 20000
#define R_REL   48
#define NBASES  12
#define E_EDGES 640000
#define KDIM    1664        // 12*128 (bases) + 128 (root)
#define KSTEPS  52          // 1664 / 32
#define SLOTS   96          // fixed CSR slots per dst (deg ~ Bin(640K,1/20K): +11 sigma)
#define CPAD    8           // cursor padding (ints): 1 counter per 32 B
#define PF      8           // gather pipeline depth

typedef __attribute__((ext_vector_type(8))) short bf16x8;
typedef __attribute__((ext_vector_type(4))) float f32x4;

// ---------- dual-dtype scalar access (flag: 1 = fp32, 0 = bf16) -------------
__device__ inline float loadF(const void* p, long long idx, int isf32) {
    if (isf32 != 0) return ((const float*)p)[idx];
    return __bfloat162float(((const __hip_bfloat16*)p)[idx]);
}

__device__ inline void storeF(void* p, long long idx, int isf32, float v) {
    if (isf32 != 0) ((float*)p)[idx] = v;
    else ((__hip_bfloat16*)p)[idx] = __float2bfloat16(v);
}

__device__ inline unsigned short toBf(float v) {
    __hip_bfloat16 h = __float2bfloat16(v);
    return *(unsigned short*)&h;
}

// ---------- zero cursors + dtype probe (fused: one dispatch) ----------------
__global__ void zero_detect(int* p, int n, const void* emb, int* flag) {
    int i = blockIdx.x * 256 + threadIdx.x;
    if (i < n) p[i] = 0;
    if (blockIdx.x == 0 && threadIdx.x == 0) {
        const unsigned short* h = (const unsigned short*)emb;
        int f32 = 0;
        for (int k = 0; k < 256; k++) {
            unsigned int bits = ((unsigned int)h[k]) << 16;
            float v = __uint_as_float(bits);
            if (!(fabsf(v) < 1000.0f)) f32 = 1;   // huge/NaN -> fp32 data
        }
        *flag = f32;
    }
}

// ---------- direct CSR-96 scatter (single atomic per edge) ------------------
__global__ void scatter_d96(const int* src, const int* dst, const int* typ,
                            int* cursordP, int* s_pack) {
    int e = blockIdx.x * 256 + threadIdx.x;
    if (e < E_EDGES) {
        int d = dst[e];
        int pos = atomicAdd(&cursordP[d * CPAD], 1);
        if (pos < SLOTS)
            s_pack[d * SLOTS + pos] = src[e] | (typ[e] << 20);
    }
}

// ---------- mkinv: per-dst relation inverse-counts, ONCE --------------------
__global__ __launch_bounds__(256) void mkinv(const int* s_pack, const int* cntP,
                                             float* inv48) {
    __shared__ int shcnt[4][R_REL];
    int tid = threadIdx.x;
    int lane = tid & 63;
    int w = tid >> 6;
    int d = blockIdx.x * 4 + w;
    int cnt = cntP[d * CPAD]; if (cnt > SLOTS) cnt = SLOTS;
    int e0 = d * SLOTS;
    int e1 = e0 + cnt;
    if (lane < R_REL) shcnt[w][lane] = 0;
    asm volatile("s_waitcnt lgkmcnt(0)" ::: "memory");
    for (int c0 = e0; c0 < e1; c0 += 64) {
        int e = c0 + lane;
        if (e < e1) atomicAdd(&shcnt[w][s_pack[e] >> 20], 1);
    }
    asm volatile("s_waitcnt lgkmcnt(0) vmcnt(0)" ::: "memory");
    if (lane < R_REL) {
        int c = shcnt[w][lane];
        inv48[(long long)d * R_REL + lane] = (c > 0) ? (1.0f / (float)c) : 0.0f;
    }
}

// ---------- Wcat build (z=0..2) + emb passthrough/xc seed (z=3), fused ------
__global__ void copy_build(const void* b0, const void* r0,
                           const void* b1, const void* r1,
                           const void* b2, const void* r2,
                           __hip_bfloat16* Wt,
                           const void* emb, void* out, float* xc,
                           const int* flagp) {
    int z = blockIdx.z;
    int isf32 = *flagp;
    if (z < 3) {
        const void* basis = (z == 0) ? b0 : (z == 1) ? b1 : b2;
        const void* root  = (z == 0) ? r0 : (z == 1) ? r1 : r2;
        int o = blockIdx.x;                       // 0..127
        int k = blockIdx.y * 256 + threadIdx.x;   // 0..1663
        if (k >= KDIM) return;
        float v;
        if (k < NBASES * 128) {
            int b = k >> 7, i = k & 127;
            v = loadF(basis, b * 16384 + i * 128 + o, isf32);
        } else {
            v = loadF(root, (k - NBASES * 128) * 128 + o, isf32);
        }
        Wt[(long long)z * (128 * KDIM) + (long long)o * KDIM + k] =
            __float2bfloat16(v);
    } else {
        int base = (blockIdx.y * 128 + blockIdx.x) * 256 + threadIdx.x;
        for (int idx = base; idx < N_NODES * 16; idx += 229376) {
            int n = idx >> 4;
            int c8 = (idx & 15) * 8;
            float4 f0, f1;
            if (isf32) {
                const float4* s = (const float4*)((const float*)emb +
                                                  (long long)n * 128 + c8);
                f0 = s[0]; f1 = s[1];
                float4* d = (float4*)((float*)out +
                                      (long long)n * 512 + 384 + c8);
                d[0] = f0;
                d[1] = f1;
            } else {
                uint4 v = *(const uint4*)((const unsigned short*)emb +
                                          (long long)n * 128 + c8);
                *(uint4*)((unsigned short*)out +
                          (long long)n * 512 + 384 + c8) = v;
                f0.x = __uint_as_float(v.x << 16);
                f0.y = __uint_as_float(v.x & 0xFFFF0000u);
                f0.z = __uint_as_float(v.y << 16);
                f0.w = __uint_as_float(v.y & 0xFFFF0000u);
                f1.x = __uint_as_float(v.z << 16);
                f1.y = __uint_as_float(v.z & 0xFFFF0000u);
                f1.z = __uint_as_float(v.w << 16);
                f1.w = __uint_as_float(v.w & 0xFFFF0000u);
            }
            float4* xd = (float4*)(xc + (long long)n * 128 + c8);
            xd[0] = f0;
            xd[1] = f1;
        }
    }
}

// ---------- aggregate: TWO waves per dst (64 cols each) ---------------------
// Column-split probe: halves per-wave state (12 acc + 8x{float,int} slots)
// to lift the 92-VGPR/5-wave residency cap; doubles wave count. Bytes
// unchanged (each wave fetches its disjoint 256B half-row). Decides whether
// the gather is concurrency-bound (win) or request-rate-bound (lose).
#define FX(j, idx) do {                                                       \
    int p_ = spkw[idx];                                                       \
    pp[j] = p_;                                                               \
    sxf[j] = xc[(long long)(p_ & 0xFFFFF) * 128 + col];                       \
} while (0)

#define CX(j) do {                                                            \
    int rel_ = pp[j] >> 20;                                                   \
    const float* cp_ = &scSw[rel_ * NBASES];                                  \
    float4 cA_ = *(const float4*)cp_;                                         \
    float4 cB_ = *(const float4*)(cp_ + 4);                                   \
    float4 cC_ = *(const float4*)(cp_ + 8);                                   \
    float x0_ = sxf[j];                                                       \
    accA[0]  += cA_.x * x0_;                                                  \
    accA[1]  += cA_.y * x0_;                                                  \
    accA[2]  += cA_.z * x0_;                                                  \
    accA[3]  += cA_.w * x0_;                                                  \
    accA[4]  += cB_.x * x0_;                                                  \
    accA[5]  += cB_.y * x0_;                                                  \
    accA[6]  += cB_.z * x0_;                                                  \
    accA[7]  += cB_.w * x0_;                                                  \
    accA[8]  += cC_.x * x0_;                                                  \
    accA[9]  += cC_.y * x0_;                                                  \
    accA[10] += cC_.z * x0_;                                                  \
    accA[11] += cC_.w * x0_;                                                  \
} while (0)

__global__ __launch_bounds__(256) void aggregate(
        const int* s_pack, const int* cntP, const float* inv48,
        const void* comp, const float* xc, unsigned short* A,
        const int* flagp) {
    __shared__ float scomp[R_REL * NBASES];      // 2304 B
    __shared__ float scS[4][R_REL * NBASES];     // 9216 B
    __shared__ int   spk[4][64];                 // 1024 B
    int isf32 = *flagp;
    int tid = threadIdx.x;
    int lane = tid & 63;
    int w = tid >> 6;
    int g = blockIdx.x * 4 + w;                  // global wave id
    int dstn = g >> 1;                           // 2 waves per dst
    int half = g & 1;
    int col = half * 64 + lane;                  // this lane's single column

    for (int i = tid; i < R_REL * NBASES; i += 256)
        scomp[i] = loadF(comp, i, isf32);
    __syncthreads();

    int cnt = cntP[dstn * CPAD]; if (cnt > SLOTS) cnt = SLOTS;
    int e0 = dstn * SLOTS;
    int e1 = e0 + cnt;
    int* spkw = spk[w];
    float* scSw = scS[w];

    // ---- scaled comp table from precomputed inv48 ----
    if (lane < R_REL) {
        float iv = inv48[(long long)dstn * R_REL + lane];
#pragma unroll
        for (int b = 0; b < NBASES; b++)
            scSw[lane * NBASES + b] = scomp[lane * NBASES + b] * iv;
    }
    asm volatile("s_waitcnt lgkmcnt(0) vmcnt(0)" ::: "memory");

    float accA[NBASES];
#pragma unroll
    for (int b = 0; b < NBASES; b++) accA[b] = 0.0f;

    // ---- PF-deep pipelined gather (wave-uniform guards) ----
    for (int c0 = e0; c0 < e1; c0 += 64) {
        {
            int e = c0 + lane;
            spkw[lane] = s_pack[(e < e1) ? e : (e1 - 1)];
        }
        asm volatile("s_waitcnt lgkmcnt(0)" ::: "memory");
        int cn = e1 - c0; if (cn > 64) cn = 64;
        float sxf[PF]; int pp[PF];
#pragma unroll
        for (int j = 0; j < PF; j++)
            if (j < cn) FX(j, j);
        int i2 = 0;
        for (; i2 + PF <= cn; i2 += PF) {
#pragma unroll
            for (int j = 0; j < PF; j++) {
                CX(j);
                if (i2 + j + PF < cn) FX(j, i2 + j + PF);
            }
        }
#pragma unroll
        for (int j = 0; j < PF; j++)
            if (i2 + j < cn) CX(j);
    }

    // ---- write A half-row: 12 basis aggregates + root slot ----
    unsigned short* Ar = A + (long long)dstn * KDIM;
#pragma unroll
    for (int b = 0; b < NBASES; b++)
        Ar[b * 128 + col] = toBf(accA[b]);
    Ar[NBASES * 128 + col] = toBf(xc[(long long)dstn * 128 + col]);
}

// ---------- dense GEMM (R8/R10-proven: 32 rows x 128 cols, 625 blocks) ------
// UNCHANGED: 4 MFMA chains/wave = the ILP the latency-bound K-loop needs.
__global__ __launch_bounds__(256) void gemm_out(
        const __hip_bfloat16* A, const __hip_bfloat16* Wt,
        const void* bias, void* out, int slot,
        float* xc, int writeXc, const int* flagp) {
    int isf32 = *flagp;
    int tid = threadIdx.x;
    int lane = tid & 63;
    int w = tid >> 6;
    int lr = lane & 15;
    int lk = lane >> 4;
    int colBase = w * 32;
    int nb = blockIdx.x;
    const __hip_bfloat16* a0p = A + (long long)(nb * 32 + lr) * KDIM;
    const __hip_bfloat16* a1p = a0p + 16 * KDIM;
    const __hip_bfloat16* w0p = Wt + (long long)(colBase + lr) * KDIM;
    const __hip_bfloat16* w1p = w0p + 16 * KDIM;
    f32x4 acc00 = {0.f, 0.f, 0.f, 0.f};
    f32x4 acc01 = {0.f, 0.f, 0.f, 0.f};
    f32x4 acc10 = {0.f, 0.f, 0.f, 0.f};
    f32x4 acc11 = {0.f, 0.f, 0.f, 0.f};
#pragma unroll 4
    for (int ks = 0; ks < KSTEPS; ks++) {
        int ko = ks * 32 + lk * 8;
        bf16x8 a0 = *(const bf16x8*)(a0p + ko);
        bf16x8 a1 = *(const bf16x8*)(a1p + ko);
        bf16x8 b0 = *(const bf16x8*)(w0p + ko);
        bf16x8 b1 = *(const bf16x8*)(w1p + ko);
        acc00 = __builtin_amdgcn_mfma_f32_16x16x32_bf16(a0, b0, acc00, 0, 0, 0);
        acc01 = __builtin_amdgcn_mfma_f32_16x16x32_bf16(a0, b1, acc01, 0, 0, 0);
        acc10 = __builtin_amdgcn_mfma_f32_16x16x32_bf16(a1, b0, acc10, 0, 0, 0);
        acc11 = __builtin_amdgcn_mfma_f32_16x16x32_bf16(a1, b1, acc11, 0, 0, 0);
    }
    float bi0 = loadF(bias, colBase + lr, isf32);
    float bi1 = loadF(bias, colBase + 16 + lr, isf32);
#pragma unroll
    for (int q = 0; q < 4; q++) {
        int row = lk * 4 + q;
        int r0 = nb * 32 + row;
        int r1 = r0 + 16;
        float v00 = fmaxf(acc00[q] + bi0, 0.0f);
        float v01 = fmaxf(acc01[q] + bi1, 0.0f);
        float v10 = fmaxf(acc10[q] + bi0, 0.0f);
        float v11 = fmaxf(acc11[q] + bi1, 0.0f);
        long long n0 = (long long)r0 * 512 + slot;
        long long n1 = (long long)r1 * 512 + slot;
        storeF(out, n0 + colBase + lr,      isf32, v00);
        storeF(out, n0 + colBase + 16 + lr, isf32, v01);
        storeF(out, n1 + colBase + lr,      isf32, v10);
        storeF(out, n1 + colBase + 16 + lr, isf32, v11);
        if (writeXc) {   // next layer's compact fp32 gather target
            xc[(long long)r0 * 128 + colBase + lr]      = v00;
            xc[(long long)r0 * 128 + colBase + 16 + lr] = v01;
            xc[(long long)r1 * 128 + colBase + lr]      = v10;
            xc[(long long)r1 * 128 + colBase + 16 + lr] = v11;
        }
    }
}

// ---------- launch -----------------------------------------------------------
extern "C" void kernel_launch(void* const* d_in, const int* in_sizes, int n_in,
                              void* d_out, int out_size, void* d_ws, size_t ws_size,
                              hipStream_t stream) {
    const void* emb  = d_in[0];
    const int* esrc = (const int*)d_in[1];
    const int* edst = (const int*)d_in[2];
    const int* etyp = (const int*)d_in[3];
    const void* comp[3];
    const void* basis[3];
    const void* root[3];
    const void* bias[3];
    for (int l = 0; l < 3; l++) {
        comp[l]  = d_in[4 + l * 4];
        basis[l] = d_in[5 + l * 4];
        root[l]  = d_in[6 + l * 4];
        bias[l]  = d_in[7 + l * 4];
    }

    char* ws = (char*)d_ws;
    int*   flag     = (int*)(ws + 0);                       // 256 B
    int*   s_pack   = (int*)(ws + 256);                     // 7,680,000 B (CSR-96)
    int*   cursordP = (int*)(ws + 7680256);                 // 640,000 B (pad 8)
    float* inv48    = (float*)(ws + 8320256);               // 3,840,000 B
    __hip_bfloat16* Wt = (__hip_bfloat16*)(ws + 12160256);  // 1,277,952 B (3 layers)
    float* xc       = (float*)(ws + 13438208);              // 10,240,000 B
    unsigned short* A = (unsigned short*)(ws + 23678208);   // 66,560,000 B
                                                            // ends 90,238,208 B

    zero_detect<<<625, 256, 0, stream>>>(cursordP, N_NODES * CPAD, emb, flag);
    scatter_d96<<<2500, 256, 0, stream>>>(esrc, edst, etyp, cursordP, s_pack);
    mkinv<<<5000, 256, 0, stream>>>(s_pack, cursordP, inv48);
    copy_build<<<dim3(128, 7, 4), 256, 0, stream>>>(
        basis[0], root[0], basis[1], root[1], basis[2], root[2], Wt,
        emb, d_out, xc, flag);

    const int slots[3] = {256, 128, 0};   // x1, x2, x3 column offsets
    for (int l = 0; l < 3; l++) {
        const __hip_bfloat16* Wtl = Wt + (long long)l * (128 * KDIM);
        aggregate<<<10000, 256, 0, stream>>>(s_pack, cursordP, inv48, comp[l],
                                             xc, A, flag);
        gemm_out<<<625, 256, 0, stream>>>((const __hip_bfloat16*)A, Wtl,
                                          bias[l], d_out, slots[l],
                                          xc, (l < 2) ? 1 : 0, flag);
    }
    (void)in_sizes; (void)n_in; (void)out_size; (void)ws_size;
}

// Round 16
// 623.986 us; speedup vs baseline: 1.4356x; 1.4356x over previous
//
#include <hip/hip_runtime.h>
#include <hip/hip_bf16.h>

#define N_NODES 20000
#define R_REL   48
#define NBASES  12
#define E_EDGES 640000
#define KDIM    1664        // 12*128 (bases) + 128 (root)
#define KSTEPS  52          // 1664 / 32
#define SLOTS   96          // fixed CSR slots per dst (deg ~ Bin(640K,1/20K): +11 sigma)
#define CPAD    8           // cursor padding (ints): 1 counter per 32 B
#define PFP     4           // pair-pipeline depth (4 pairs = 8 edges in flight)

typedef __attribute__((ext_vector_type(8))) short bf16x8;
typedef __attribute__((ext_vector_type(4))) float f32x4;

// ---------- dual-dtype scalar access (flag: 1 = fp32, 0 = bf16) -------------
__device__ inline float loadF(const void* p, long long idx, int isf32) {
    if (isf32 != 0) return ((const float*)p)[idx];
    return __bfloat162float(((const __hip_bfloat16*)p)[idx]);
}

__device__ inline void storeF(void* p, long long idx, int isf32, float v) {
    if (isf32 != 0) ((float*)p)[idx] = v;
    else ((__hip_bfloat16*)p)[idx] = __float2bfloat16(v);
}

__device__ inline unsigned short toBf(float v) {
    __hip_bfloat16 h = __float2bfloat16(v);
    return *(unsigned short*)&h;
}

// ---------- zero cursors + dtype probe (fused: one dispatch) ----------------
__global__ void zero_detect(int* p, int n, const void* emb, int* flag) {
    int i = blockIdx.x * 256 + threadIdx.x;
    if (i < n) p[i] = 0;
    if (blockIdx.x == 0 && threadIdx.x == 0) {
        const unsigned short* h = (const unsigned short*)emb;
        int f32 = 0;
        for (int k = 0; k < 256; k++) {
            unsigned int bits = ((unsigned int)h[k]) << 16;
            float v = __uint_as_float(bits);
            if (!(fabsf(v) < 1000.0f)) f32 = 1;   // huge/NaN -> fp32 data
        }
        *flag = f32;
    }
}

// ---------- direct CSR-96 scatter (single atomic per edge) ------------------
__global__ void scatter_d96(const int* src, const int* dst, const int* typ,
                            int* cursordP, int* s_pack) {
    int e = blockIdx.x * 256 + threadIdx.x;
    if (e < E_EDGES) {
        int d = dst[e];
        int pos = atomicAdd(&cursordP[d * CPAD], 1);
        if (pos < SLOTS)
            s_pack[d * SLOTS + pos] = src[e] | (typ[e] << 20);
    }
}

// ---------- mkinv: per-dst relation inverse-counts + tail sentinel ----------
// Sentinel pack (rel=48 -> zeroed comp row) at slot cnt pads odd counts so
// aggregate's 2-edges-per-instruction pipeline needs no divergent tail.
__global__ __launch_bounds__(256) void mkinv(int* s_pack, const int* cntP,
                                             float* inv48) {
    __shared__ int shcnt[4][R_REL];
    int tid = threadIdx.x;
    int lane = tid & 63;
    int w = tid >> 6;
    int d = blockIdx.x * 4 + w;
    int cnt = cntP[d * CPAD]; if (cnt > SLOTS) cnt = SLOTS;
    int e0 = d * SLOTS;
    int e1 = e0 + cnt;
    if (lane < R_REL) shcnt[w][lane] = 0;
    asm volatile("s_waitcnt lgkmcnt(0)" ::: "memory");
    for (int c0 = e0; c0 < e1; c0 += 64) {
        int e = c0 + lane;
        if (e < e1) atomicAdd(&shcnt[w][s_pack[e] >> 20], 1);
    }
    asm volatile("s_waitcnt lgkmcnt(0) vmcnt(0)" ::: "memory");
    if (lane < R_REL) {
        int c = shcnt[w][lane];
        inv48[(long long)d * R_REL + lane] = (c > 0) ? (1.0f / (float)c) : 0.0f;
    }
    if (lane == 0 && cnt < SLOTS)
        s_pack[e0 + cnt] = (R_REL << 20);   // sentinel: rel=48, src=0
}

// ---------- Wcat build (z=0..2) + emb passthrough/xc seed (z=3), fused ------
__global__ void copy_build(const void* b0, const void* r0,
                           const void* b1, const void* r1,
                           const void* b2, const void* r2,
                           __hip_bfloat16* Wt,
                           const void* emb, void* out, float* xc,
                           const int* flagp) {
    int z = blockIdx.z;
    int isf32 = *flagp;
    if (z < 3) {
        const void* basis = (z == 0) ? b0 : (z == 1) ? b1 : b2;
        const void* root  = (z == 0) ? r0 : (z == 1) ? r1 : r2;
        int o = blockIdx.x;                       // 0..127
        int k = blockIdx.y * 256 + threadIdx.x;   // 0..1663
        if (k >= KDIM) return;
        float v;
        if (k < NBASES * 128) {
            int b = k >> 7, i = k & 127;
            v = loadF(basis, b * 16384 + i * 128 + o, isf32);
        } else {
            v = loadF(root, (k - NBASES * 128) * 128 + o, isf32);
        }
        Wt[(long long)z * (128 * KDIM) + (long long)o * KDIM + k] =
            __float2bfloat16(v);
    } else {
        int base = (blockIdx.y * 128 + blockIdx.x) * 256 + threadIdx.x;
        for (int idx = base; idx < N_NODES * 16; idx += 229376) {
            int n = idx >> 4;
            int c8 = (idx & 15) * 8;
            float4 f0, f1;
            if (isf32) {
                const float4* s = (const float4*)((const float*)emb +
                                                  (long long)n * 128 + c8);
                f0 = s[0]; f1 = s[1];
                float4* d = (float4*)((float*)out +
                                      (long long)n * 512 + 384 + c8);
                d[0] = f0;
                d[1] = f1;
            } else {
                uint4 v = *(const uint4*)((const unsigned short*)emb +
                                          (long long)n * 128 + c8);
                *(uint4*)((unsigned short*)out +
                          (long long)n * 512 + 384 + c8) = v;
                f0.x = __uint_as_float(v.x << 16);
                f0.y = __uint_as_float(v.x & 0xFFFF0000u);
                f0.z = __uint_as_float(v.y << 16);
                f0.w = __uint_as_float(v.y & 0xFFFF0000u);
                f1.x = __uint_as_float(v.z << 16);
                f1.y = __uint_as_float(v.z & 0xFFFF0000u);
                f1.z = __uint_as_float(v.w << 16);
                f1.w = __uint_as_float(v.w & 0xFFFF0000u);
            }
            float4* xd = (float4*)(xc + (long long)n * 128 + c8);
            xd[0] = f0;
            xd[1] = f1;
        }
    }
}

// ---------- aggregate: ONE wave per dst, TWO edges per gather instruction ---
// R15 proved the gather is bound by instruction count (2x insts -> 2.16x
// time, same bytes/occupancy+10pts). So: float4/lane, lanes 0-31 = edge e's
// 128 cols, lanes 32-63 = edge e+1 -> HALF the gather insts of R14. 48
// acc/lane; halves merged once per dst via shfl_xor(32). Sentinel (rel=48,
// zero comp) pads odd counts -> uniform guards.
#define FXP(j, pr) do {                                                       \
    int p_ = spkw[((pr) << 1) | eh];                                          \
    rl[j] = p_ >> 20;                                                         \
    sx[j] = *(const float4*)(xc + (long long)(p_ & 0xFFFFF) * 128 + col4);    \
} while (0)

#define CXP(j) do {                                                           \
    const float* cp_ = &scSw[rl[j] * NBASES];                                 \
    float4 cA_ = *(const float4*)cp_;                                         \
    float4 cB_ = *(const float4*)(cp_ + 4);                                   \
    float4 cC_ = *(const float4*)(cp_ + 8);                                   \
    float4 x_ = sx[j];                                                        \
    float cb_;                                                                \
    cb_ = cA_.x; acc[0]  += cb_*x_.x; acc[1]  += cb_*x_.y;                    \
                 acc[2]  += cb_*x_.z; acc[3]  += cb_*x_.w;                    \
    cb_ = cA_.y; acc[4]  += cb_*x_.x; acc[5]  += cb_*x_.y;                    \
                 acc[6]  += cb_*x_.z; acc[7]  += cb_*x_.w;                    \
    cb_ = cA_.z; acc[8]  += cb_*x_.x; acc[9]  += cb_*x_.y;                    \
                 acc[10] += cb_*x_.z; acc[11] += cb_*x_.w;                    \
    cb_ = cA_.w; acc[12] += cb_*x_.x; acc[13] += cb_*x_.y;                    \
                 acc[14] += cb_*x_.z; acc[15] += cb_*x_.w;                    \
    cb_ = cB_.x; acc[16] += cb_*x_.x; acc[17] += cb_*x_.y;                    \
                 acc[18] += cb_*x_.z; acc[19] += cb_*x_.w;                    \
    cb_ = cB_.y; acc[20] += cb_*x_.x; acc[21] += cb_*x_.y;                    \
                 acc[22] += cb_*x_.z; acc[23] += cb_*x_.w;                    \
    cb_ = cB_.z; acc[24] += cb_*x_.x; acc[25] += cb_*x_.y;                    \
                 acc[26] += cb_*x_.z; acc[27] += cb_*x_.w;                    \
    cb_ = cB_.w; acc[28] += cb_*x_.x; acc[29] += cb_*x_.y;                    \
                 acc[30] += cb_*x_.z; acc[31] += cb_*x_.w;                    \
    cb_ = cC_.x; acc[32] += cb_*x_.x; acc[33] += cb_*x_.y;                    \
                 acc[34] += cb_*x_.z; acc[35] += cb_*x_.w;                    \
    cb_ = cC_.y; acc[36] += cb_*x_.x; acc[37] += cb_*x_.y;                    \
                 acc[38] += cb_*x_.z; acc[39] += cb_*x_.w;                    \
    cb_ = cC_.z; acc[40] += cb_*x_.x; acc[41] += cb_*x_.y;                    \
                 acc[42] += cb_*x_.z; acc[43] += cb_*x_.w;                    \
    cb_ = cC_.w; acc[44] += cb_*x_.x; acc[45] += cb_*x_.y;                    \
                 acc[46] += cb_*x_.z; acc[47] += cb_*x_.w;                    \
} while (0)

__global__ __launch_bounds__(256) void aggregate(
        const int* s_pack, const int* cntP, const float* inv48,
        const void* comp, const float* xc, unsigned short* A,
        const int* flagp) {
    __shared__ float scomp[R_REL * NBASES];           // 2304 B
    __shared__ float scS[4][(R_REL + 1) * NBASES];    // 9408 B (rel 48 = zeros)
    __shared__ int   spk[4][64];                      // 1024 B
    int isf32 = *flagp;
    int tid = threadIdx.x;
    int lane = tid & 63;
    int w = tid >> 6;
    int dstn = blockIdx.x * 4 + w;
    int eh = lane >> 5;              // edge half: 0 = even edge, 1 = odd edge
    int col4 = (lane & 31) * 4;      // this lane's 4 columns

    for (int i = tid; i < R_REL * NBASES; i += 256)
        scomp[i] = loadF(comp, i, isf32);
    __syncthreads();

    int cnt = cntP[dstn * CPAD]; if (cnt > SLOTS) cnt = SLOTS;
    int e0 = dstn * SLOTS;
    int e1 = e0 + cnt;
    int cntE = cnt + (cnt & 1);      // even-padded (sentinel at e0+cnt if odd)
    int eLast = e0 + cntE - 1;       // last readable slot
    int* spkw = spk[w];
    float* scSw = scS[w];

    // ---- scaled comp table (rels 0..47 from inv48; rel 48 = zeros) ----
    if (lane <= R_REL) {
        float iv = (lane < R_REL)
                       ? inv48[(long long)dstn * R_REL + lane] : 0.0f;
        int lsrc = (lane < R_REL) ? lane : 0;
#pragma unroll
        for (int b = 0; b < NBASES; b++)
            scSw[lane * NBASES + b] = scomp[lsrc * NBASES + b] * iv;
    }
    asm volatile("s_waitcnt lgkmcnt(0) vmcnt(0)" ::: "memory");

    float acc[48];
#pragma unroll
    for (int k = 0; k < 48; k++) acc[k] = 0.0f;

    // ---- pair-pipelined gather (wave-uniform guards) ----
    for (int c0 = e0; c0 < e1; c0 += 64) {
        {
            int e = c0 + lane;
            spkw[lane] = s_pack[(e < eLast) ? e : eLast];
        }
        asm volatile("s_waitcnt lgkmcnt(0)" ::: "memory");
        int cn = e1 - c0; if (cn > 64) cn = 64;
        int cnP = (cn + 1) >> 1;     // pairs (sentinel covers odd tail)
        float4 sx[PFP]; int rl[PFP];
#pragma unroll
        for (int j = 0; j < PFP; j++)
            if (j < cnP) FXP(j, j);
        int i2 = 0;
        for (; i2 + PFP <= cnP; i2 += PFP) {
#pragma unroll
            for (int j = 0; j < PFP; j++) {
                CXP(j);
                if (i2 + j + PFP < cnP) FXP(j, i2 + j + PFP);
            }
        }
#pragma unroll
        for (int j = 0; j < PFP; j++)
            if (i2 + j < cnP) CXP(j);
    }

    // ---- merge edge-halves: lane L += lane L^32 (both halves, same cols) --
#pragma unroll
    for (int k = 0; k < 48; k++) acc[k] += __shfl_xor(acc[k], 32);

    // ---- lanes 0..31 write A row: 12 basis aggregates + root slot ----
    if (lane < 32) {
        unsigned short* Ar = A + (long long)dstn * KDIM;
#pragma unroll
        for (int b = 0; b < NBASES; b++) {
            uint2 pk;
            pk.x = ((unsigned int)toBf(acc[b * 4 + 1]) << 16) |
                   (unsigned int)toBf(acc[b * 4 + 0]);
            pk.y = ((unsigned int)toBf(acc[b * 4 + 3]) << 16) |
                   (unsigned int)toBf(acc[b * 4 + 2]);
            *(uint2*)(Ar + b * 128 + col4) = pk;
        }
        float4 f = *(const float4*)(xc + (long long)dstn * 128 + col4);
        uint2 pk;
        pk.x = ((unsigned int)toBf(f.y) << 16) | (unsigned int)toBf(f.x);
        pk.y = ((unsigned int)toBf(f.w) << 16) | (unsigned int)toBf(f.z);
        *(uint2*)(Ar + NBASES * 128 + col4) = pk;
    }
}

// ---------- dense GEMM (R8/R10-proven: 32 rows x 128 cols, 625 blocks) ------
// UNCHANGED: 4 MFMA chains/wave = the ILP the latency-bound K-loop needs.
__global__ __launch_bounds__(256) void gemm_out(
        const __hip_bfloat16* A, const __hip_bfloat16* Wt,
        const void* bias, void* out, int slot,
        float* xc, int writeXc, const int* flagp) {
    int isf32 = *flagp;
    int tid = threadIdx.x;
    int lane = tid & 63;
    int w = tid >> 6;
    int lr = lane & 15;
    int lk = lane >> 4;
    int colBase = w * 32;
    int nb = blockIdx.x;
    const __hip_bfloat16* a0p = A + (long long)(nb * 32 + lr) * KDIM;
    const __hip_bfloat16* a1p = a0p + 16 * KDIM;
    const __hip_bfloat16* w0p = Wt + (long long)(colBase + lr) * KDIM;
    const __hip_bfloat16* w1p = w0p + 16 * KDIM;
    f32x4 acc00 = {0.f, 0.f, 0.f, 0.f};
    f32x4 acc01 = {0.f, 0.f, 0.f, 0.f};
    f32x4 acc10 = {0.f, 0.f, 0.f, 0.f};
    f32x4 acc11 = {0.f, 0.f, 0.f, 0.f};
#pragma unroll 4
    for (int ks = 0; ks < KSTEPS; ks++) {
        int ko = ks * 32 + lk * 8;
        bf16x8 a0 = *(const bf16x8*)(a0p + ko);
        bf16x8 a1 = *(const bf16x8*)(a1p + ko);
        bf16x8 b0 = *(const bf16x8*)(w0p + ko);
        bf16x8 b1 = *(const bf16x8*)(w1p + ko);
        acc00 = __builtin_amdgcn_mfma_f32_16x16x32_bf16(a0, b0, acc00, 0, 0, 0);
        acc01 = __builtin_amdgcn_mfma_f32_16x16x32_bf16(a0, b1, acc01, 0, 0, 0);
        acc10 = __builtin_amdgcn_mfma_f32_16x16x32_bf16(a1, b0, acc10, 0, 0, 0);
        acc11 = __builtin_amdgcn_mfma_f32_16x16x32_bf16(a1, b1, acc11, 0, 0, 0);
    }
    float bi0 = loadF(bias, colBase + lr, isf32);
    float bi1 = loadF(bias, colBase + 16 + lr, isf32);
#pragma unroll
    for (int q = 0; q < 4; q++) {
        int row = lk * 4 + q;
        int r0 = nb * 32 + row;
        int r1 = r0 + 16;
        float v00 = fmaxf(acc00[q] + bi0, 0.0f);
        float v01 = fmaxf(acc01[q] + bi1, 0.0f);
        float v10 = fmaxf(acc10[q] + bi0, 0.0f);
        float v11 = fmaxf(acc11[q] + bi1, 0.0f);
        long long n0 = (long long)r0 * 512 + slot;
        long long n1 = (long long)r1 * 512 + slot;
        storeF(out, n0 + colBase + lr,      isf32, v00);
        storeF(out, n0 + colBase + 16 + lr, isf32, v01);
        storeF(out, n1 + colBase + lr,      isf32, v10);
        storeF(out, n1 + colBase + 16 + lr, isf32, v11);
        if (writeXc) {   // next layer's compact fp32 gather target
            xc[(long long)r0 * 128 + colBase + lr]      = v00;
            xc[(long long)r0 * 128 + colBase + 16 + lr] = v01;
            xc[(long long)r1 * 128 + colBase + lr]      = v10;
            xc[(long long)r1 * 128 + colBase + 16 + lr] = v11;
        }
    }
}

// ---------- launch -----------------------------------------------------------
extern "C" void kernel_launch(void* const* d_in, const int* in_sizes, int n_in,
                              void* d_out, int out_size, void* d_ws, size_t ws_size,
                              hipStream_t stream) {
    const void* emb  = d_in[0];
    const int* esrc = (const int*)d_in[1];
    const int* edst = (const int*)d_in[2];
    const int* etyp = (const int*)d_in[3];
    const void* comp[3];
    const void* basis[3];
    const void* root[3];
    const void* bias[3];
    for (int l = 0; l < 3; l++) {
        comp[l]  = d_in[4 + l * 4];
        basis[l] = d_in[5 + l * 4];
        root[l]  = d_in[6 + l * 4];
        bias[l]  = d_in[7 + l * 4];
    }

    char* ws = (char*)d_ws;
    int*   flag     = (int*)(ws + 0);                       // 256 B
    int*   s_pack   = (int*)(ws + 256);                     // 7,680,000 B (CSR-96)
    int*   cursordP = (int*)(ws + 7680256);                 // 640,000 B (pad 8)
    float* inv48    = (float*)(ws + 8320256);               // 3,840,000 B
    __hip_bfloat16* Wt = (__hip_bfloat16*)(ws + 12160256);  // 1,277,952 B (3 layers)
    float* xc       = (float*)(ws + 13438208);              // 10,240,000 B
    unsigned short* A = (unsigned short*)(ws + 23678208);   // 66,560,000 B
                                                            // ends 90,238,208 B

    zero_detect<<<625, 256, 0, stream>>>(cursordP, N_NODES * CPAD, emb, flag);
    scatter_d96<<<2500, 256, 0, stream>>>(esrc, edst, etyp, cursordP, s_pack);
    mkinv<<<5000, 256, 0, stream>>>(s_pack, cursordP, inv48);
    copy_build<<<dim3(128, 7, 4), 256, 0, stream>>>(
        basis[0], root[0], basis[1], root[1], basis[2], root[2], Wt,
        emb, d_out, xc, flag);

    const int slots[3] = {256, 128, 0};   // x1, x2, x3 column offsets
    for (int l = 0; l < 3; l++) {
        const __hip_bfloat16* Wtl = Wt + (long long)l * (128 * KDIM);
        aggregate<<<5000, 256, 0, stream>>>(s_pack, cursordP, inv48, comp[l],
                                            xc, A, flag);
        gemm_out<<<625, 256, 0, stream>>>((const __hip_bfloat16*)A, Wtl,
                                          bias[l], d_out, slots[l],
                                          xc, (l < 2) ? 1 : 0, flag);
    }
    (void)in_sizes; (void)n_in; (void)out_size; (void)ws_size;
}